// Round 2
// baseline (151.711 us; speedup 1.0000x reference)
//
#include <hip/hip_runtime.h>
#include <hip/hip_bf16.h>
#include <stdint.h>

// HausdorffLoss: N=M=4096, D=1024 fp32 in, scalar fp32 out.
// bf16 MFMA GEMM (256x256 tile, 8-wave, 4-phase/K-tile counted-vmcnt pipeline)
// + fp32 norms + fused min epilogue.

#define NPTS 4096
#define MPTS 4096
#define DDIM 1024
#define SLOTB 32768   // bytes per ring slot (A-Khalf 16KB + B-Khalf 16KB, interleaved)

typedef __attribute__((ext_vector_type(8))) short bf16x8;
typedef __attribute__((ext_vector_type(4))) float f32x4;

__device__ __forceinline__ unsigned short f2bf(float f) {
    unsigned int u = __float_as_uint(f);
    unsigned int r = 0x7FFFu + ((u >> 16) & 1u);   // RNE
    return (unsigned short)((u + r) >> 16);
}

__device__ __forceinline__ void gl_lds16(const void* g, void* l) {
    __builtin_amdgcn_global_load_lds(
        (const __attribute__((address_space(1))) unsigned int*)g,
        (__attribute__((address_space(3))) unsigned int*)l, 16, 0, 0);
}

// ---------------- prepass: fp32 -> bf16 + row squared norms + min-init -----
// One wave per row; 4 rows per 256-thread block; 2048 blocks.
__global__ __launch_bounds__(256) void prepass_kernel(
    const float* __restrict__ s1, const float* __restrict__ s2,
    unsigned short* __restrict__ b1, unsigned short* __restrict__ b2,
    float* __restrict__ norms, unsigned int* __restrict__ mins) {
    const int row = blockIdx.x * 4 + (threadIdx.x >> 6);
    const int lane = threadIdx.x & 63;
    const float* src;
    unsigned short* dst;
    if (row < NPTS) { src = s1 + (size_t)row * DDIM; dst = b1 + (size_t)row * DDIM; }
    else            { src = s2 + (size_t)(row - NPTS) * DDIM; dst = b2 + (size_t)(row - NPTS) * DDIM; }
    float sq = 0.f;
    #pragma unroll
    for (int i = 0; i < 4; ++i) {
        float4 v = ((const float4*)src)[lane + i * 64];
        sq += v.x * v.x + v.y * v.y + v.z * v.z + v.w * v.w;
        ushort4 o;
        o.x = f2bf(v.x); o.y = f2bf(v.y); o.z = f2bf(v.z); o.w = f2bf(v.w);
        ((ushort4*)dst)[lane + i * 64] = o;
    }
    #pragma unroll
    for (int off = 32; off; off >>= 1) sq += __shfl_down(sq, off, 64);
    if (lane == 0) { norms[row] = sq; mins[row] = 0x7f7f7f7fu; }
}

// ---------------- fused GEMM + min epilogue --------------------------------
// 256x256 tile, BK=64 (2 K-half units/tile), 8 waves (2Mx4N), 512 threads.
// LDS: 4-slot ring, slot = unit&3; unit u = K-half (u>>1 = tile, u&1 = half).
// LDS row r (128B) holds A-row-r 64B || B-row-r 64B, XOR-swizzled by chunk:
//   stored chunk c contains nominal chunk c^(r&7).

// stage 2 of unit u's 4 global_load_lds issues (i0 = 0 or 2); per-thread.
#define STAGE2(u, i0) do {                                                      \
    if ((u) < 32) {                                                             \
        const int slot_ = (u) & 3;                                              \
        const int k0_ = ((u) >> 1) * 64 + ((u) & 1) * 32;                       \
        _Pragma("unroll")                                                       \
        for (int ii_ = 0; ii_ < 2; ++ii_) {                                     \
            const int i_ = (i0) + ii_;                                          \
            const int row_ = i_ * 64 + wave * 8 + srow_l;                       \
            const unsigned short* g_ = (sc < 4)                                 \
                ? (Ab + (size_t)row_ * DDIM + k0_ + sc * 8)                     \
                : (Bb + (size_t)row_ * DDIM + k0_ + (sc - 4) * 8);              \
            gl_lds16(g_, ldsb + slot_ * SLOTB + i_ * 8192 + wave * 1024);       \
        }                                                                       \
    }                                                                           \
} while (0)

// One phase: ds-reads || stage 2 loads -> barrier -> lgkm(0) -> 16 MFMA -> barrier.
// FH: 0 = fragment rows 0-63 of the wave's 128 (also loads bf), 1 = rows 64-127.
#define PHASE(slot_, FH, STAGECALL, ENDWAIT) do {                               \
    bf16x8 af_[4];                                                              \
    if ((FH) == 0) {                                                            \
        _Pragma("unroll")                                                       \
        for (int fj_ = 0; fj_ < 4; ++fj_) {                                     \
            const int col_ = wc * 64 + fj_ * 16 + r0;                           \
            bf[fj_] = *(const bf16x8*)(ldsb + (slot_) * SLOTB + col_ * 128 + chunkB); \
        }                                                                       \
    }                                                                           \
    _Pragma("unroll")                                                           \
    for (int fl_ = 0; fl_ < 4; ++fl_) {                                         \
        const int arow_ = wr * 128 + (FH) * 64 + fl_ * 16 + r0;                 \
        af_[fl_] = *(const bf16x8*)(ldsb + (slot_) * SLOTB + arow_ * 128 + chunkA); \
    }                                                                           \
    STAGECALL;                                                                  \
    __builtin_amdgcn_s_barrier();                                               \
    asm volatile("s_waitcnt lgkmcnt(0)" ::: "memory");                          \
    __builtin_amdgcn_sched_barrier(0);                                          \
    __builtin_amdgcn_s_setprio(1);                                              \
    _Pragma("unroll")                                                           \
    for (int fl_ = 0; fl_ < 4; ++fl_)                                           \
        _Pragma("unroll")                                                       \
        for (int fj_ = 0; fj_ < 4; ++fj_)                                       \
            acc[(FH) * 4 + fl_][fj_] = __builtin_amdgcn_mfma_f32_16x16x32_bf16( \
                af_[fl_], bf[fj_], acc[(FH) * 4 + fl_][fj_], 0, 0, 0);          \
    __builtin_amdgcn_s_setprio(0);                                              \
    ENDWAIT;                                                                    \
    __builtin_amdgcn_s_barrier();                                               \
    __builtin_amdgcn_sched_barrier(0);                                          \
} while (0)

__global__ __launch_bounds__(512, 2) void cham_gemm_kernel(
    const unsigned short* __restrict__ A,   // set1 bf16 [4096][1024]
    const unsigned short* __restrict__ B,   // set2 bf16 [4096][1024]
    const float* __restrict__ x2, const float* __restrict__ y2,
    unsigned int* __restrict__ rowmin, unsigned int* __restrict__ colmin) {
    __shared__ __align__(16) unsigned short lds_us[65536];   // 128 KB
    char* ldsb = (char*)lds_us;

    const int bi = blockIdx.x & 15;
    const int bj = blockIdx.x >> 4;
    const int tid = threadIdx.x;
    const int wave = tid >> 6;
    const int lane = tid & 63;
    const int wr = wave >> 2;          // 0..1  (128 rows each)
    const int wc = wave & 3;           // 0..3  (64 cols each)
    const int r0 = lane & 15;
    const int q = lane >> 4;           // k-subchunk 0..3

    // lane-constant swizzled chunk offsets (bits 4-6)
    const int chunkA = ((q ^ (r0 & 7)) << 4);
    const int chunkB = (((4 + q) ^ (r0 & 7)) << 4);

    // staging lane constants
    const int srow_l = lane >> 3;      // row within the wave's 8-row strip
    const int sc = (lane & 7) ^ srow_l; // inverse-swizzled source chunk

    const unsigned short* Ab = A + (size_t)(bi * 256) * DDIM;
    const unsigned short* Bb = B + (size_t)(bj * 256) * DDIM;

    f32x4 acc[8][4];
    #pragma unroll
    for (int i = 0; i < 8; ++i)
        #pragma unroll
        for (int j = 0; j < 4; ++j)
            acc[i][j] = (f32x4){0.f, 0.f, 0.f, 0.f};

    bf16x8 bf[4];

    // prologue: stage units 0,1,2 (12 loads/thread); wait for units 0,1.
    STAGE2(0, 0); STAGE2(0, 2);
    STAGE2(1, 0); STAGE2(1, 2);
    STAGE2(2, 0); STAGE2(2, 2);
    asm volatile("s_waitcnt vmcnt(4)" ::: "memory");
    __builtin_amdgcn_s_barrier();
    __builtin_amdgcn_sched_barrier(0);

    #pragma unroll 2
    for (int t = 0; t < 16; ++t) {
        const int s0 = (2 * t) & 3;
        const int s1 = (2 * t + 1) & 3;
        const int u0 = 2 * t + 3;
        const int u1 = 2 * t + 4;
        PHASE(s0, 0, STAGE2(u0, 0), );
        PHASE(s0, 1, STAGE2(u0, 2), );
        PHASE(s1, 0, STAGE2(u1, 0), );
        PHASE(s1, 1, STAGE2(u1, 2),
              if (t == 14) { asm volatile("s_waitcnt vmcnt(0)" ::: "memory"); }
              else if (t < 14) { asm volatile("s_waitcnt vmcnt(4)" ::: "memory"); });
    }

    // ---- epilogue: dist = (x2[n] + y2[m] - 2*xy)/D, fused row/col mins
    const float invD = 1.0f / (float)DDIM;
    const int nb = bi * 256 + wr * 128;
    const int mb = bj * 256 + wc * 64;

    float y2v[4];
    #pragma unroll
    for (int fj = 0; fj < 4; ++fj) y2v[fj] = y2[mb + fj * 16 + r0];

    float cv[4];
    #pragma unroll
    for (int fj = 0; fj < 4; ++fj) cv[fj] = 3.0e38f;

    #pragma unroll
    for (int fi = 0; fi < 8; ++fi) {
        #pragma unroll
        for (int rg = 0; rg < 4; ++rg) {
            const int n = nb + fi * 16 + q * 4 + rg;
            const float x2v = x2[n];
            float rv = 3.0e38f;
            #pragma unroll
            for (int fj = 0; fj < 4; ++fj) {
                float d = (x2v + y2v[fj] - 2.0f * acc[fi][fj][rg]) * invD;
                rv = fminf(rv, d);
                cv[fj] = fminf(cv[fj], d);
            }
            rv = fminf(rv, __shfl_xor(rv, 1, 64));
            rv = fminf(rv, __shfl_xor(rv, 2, 64));
            rv = fminf(rv, __shfl_xor(rv, 4, 64));
            rv = fminf(rv, __shfl_xor(rv, 8, 64));
            if (r0 == 0) atomicMin(&rowmin[n], __float_as_uint(rv));
        }
    }

    #pragma unroll
    for (int fj = 0; fj < 4; ++fj) {
        float v = cv[fj];
        v = fminf(v, __shfl_xor(v, 16, 64));
        v = fminf(v, __shfl_xor(v, 32, 64));
        if (lane < 16) atomicMin(&colmin[mb + fj * 16 + lane], __float_as_uint(v));
    }
}

// ---------------- final reduction ------------------------------------------
__global__ __launch_bounds__(1024) void finredux_kernel(
    const unsigned int* __restrict__ mins /* 8192 */, float* __restrict__ out) {
    int t = threadIdx.x;
    float s = 0.f;
    #pragma unroll
    for (int i = 0; i < 8; ++i) s += __uint_as_float(mins[t + i * 1024]);
    #pragma unroll
    for (int off = 32; off; off >>= 1) s += __shfl_down(s, off, 64);
    __shared__ float ws_[16];
    if ((t & 63) == 0) ws_[t >> 6] = s;
    __syncthreads();
    if (t == 0) {
        float tot = 0.f;
        #pragma unroll
        for (int i = 0; i < 16; ++i) tot += ws_[i];
        out[0] = tot * (1.0f / 8192.0f);
    }
}

extern "C" void kernel_launch(void* const* d_in, const int* in_sizes, int n_in,
                              void* d_out, int out_size, void* d_ws, size_t ws_size,
                              hipStream_t stream) {
    const float* s1 = (const float*)d_in[0];
    const float* s2 = (const float*)d_in[1];
    char* ws = (char*)d_ws;

    unsigned short* b1 = (unsigned short*)ws;                         //  8 MB
    unsigned short* b2 = (unsigned short*)(ws + 8388608);             //  8 MB
    float* norms       = (float*)(ws + 16777216);                     // 32 KB
    unsigned int* mins = (unsigned int*)(ws + 16777216 + 32768);      // 32 KB
    float* out = (float*)d_out;

    prepass_kernel<<<2048, 256, 0, stream>>>(s1, s2, b1, b2, norms, mins);
    cham_gemm_kernel<<<256, 512, 0, stream>>>(b1, b2, norms, norms + NPTS,
                                              mins, mins + NPTS);
    finredux_kernel<<<1, 1024, 0, stream>>>(mins, out);
}

// Round 3
// 123.765 us; speedup vs baseline: 1.2258x; 1.2258x over previous
//
#include <hip/hip_runtime.h>
#include <hip/hip_bf16.h>
#include <stdint.h>

// HausdorffLoss: N=M=4096, D=1024 fp32 in, scalar fp32 out.
// bf16 MFMA GEMM: 256x256 tile, 8 waves (2Mx4N), quadrant-phase schedule
// (m201-style), 2-buffer LDS, counted vmcnt(4) once per K-tile.

#define NPTS 4096
#define MPTS 4096
#define DDIM 1024

typedef __attribute__((ext_vector_type(8))) short bf16x8;
typedef __attribute__((ext_vector_type(4))) float f32x4;

__device__ __forceinline__ unsigned short f2bf(float f) {
    unsigned int u = __float_as_uint(f);
    unsigned int r = 0x7FFFu + ((u >> 16) & 1u);   // RNE
    return (unsigned short)((u + r) >> 16);
}

__device__ __forceinline__ void gl_lds16(const void* g, void* l) {
    __builtin_amdgcn_global_load_lds(
        (const __attribute__((address_space(1))) unsigned int*)g,
        (__attribute__((address_space(3))) unsigned int*)l, 16, 0, 0);
}

// ---------------- prepass: fp32 -> bf16 + row squared norms + min-init -----
__global__ __launch_bounds__(256) void prepass_kernel(
    const float* __restrict__ s1, const float* __restrict__ s2,
    unsigned short* __restrict__ b1, unsigned short* __restrict__ b2,
    float* __restrict__ norms, unsigned int* __restrict__ mins) {
    const int row = blockIdx.x * 4 + (threadIdx.x >> 6);
    const int lane = threadIdx.x & 63;
    const float* src;
    unsigned short* dst;
    if (row < NPTS) { src = s1 + (size_t)row * DDIM; dst = b1 + (size_t)row * DDIM; }
    else            { src = s2 + (size_t)(row - NPTS) * DDIM; dst = b2 + (size_t)(row - NPTS) * DDIM; }
    float sq = 0.f;
    #pragma unroll
    for (int i = 0; i < 4; ++i) {
        float4 v = ((const float4*)src)[lane + i * 64];
        sq += v.x * v.x + v.y * v.y + v.z * v.z + v.w * v.w;
        ushort4 o;
        o.x = f2bf(v.x); o.y = f2bf(v.y); o.z = f2bf(v.z); o.w = f2bf(v.w);
        ((ushort4*)dst)[lane + i * 64] = o;
    }
    #pragma unroll
    for (int off = 32; off; off >>= 1) sq += __shfl_down(sq, off, 64);
    if (lane == 0) { norms[row] = sq; mins[row] = 0x7f7f7f7fu; }
}

// ---------------- fused GEMM + min epilogue --------------------------------
// LDS buffer (64KB each, 2 buffers): A rows 0..255 at +0 (128B/row, XOR-
// swizzled chunks), B cols 0..255 at +32768. Half regions (16KB):
// A0=+0, A1=+16384, B0=+32768, B1=+49152.

// stage one 16KB half: 2 x global_load_lds per thread (8KB per issue).
#define STAGE_H(ldsBase, gRowBase, kcol) do {                                   \
    gl_lds16((gRowBase) + (size_t)(wave * 8 + srow) * DDIM + (kcol) + schoff,   \
             ldsb + (ldsBase) + wave * 1024);                                   \
    gl_lds16((gRowBase) + (size_t)(64 + wave * 8 + srow) * DDIM + (kcol) + schoff, \
             ldsb + (ldsBase) + 8192 + wave * 1024);                            \
} while (0)

#define RD_A(CURB, aq) do {                                                     \
    _Pragma("unroll")                                                           \
    for (int fl_ = 0; fl_ < 4; ++fl_) {                                         \
        const int row_ = wr * 128 + (aq) * 64 + fl_ * 16 + r0;                  \
        af[fl_][0] = *(const bf16x8*)(ldsb + (CURB) + row_ * 128 + ch0);        \
        af[fl_][1] = *(const bf16x8*)(ldsb + (CURB) + row_ * 128 + ch1);        \
    }                                                                           \
} while (0)

#define RD_B(CURB, bq, dst) do {                                                \
    _Pragma("unroll")                                                           \
    for (int fj_ = 0; fj_ < 2; ++fj_) {                                         \
        const int col_ = wc * 64 + (bq) * 32 + fj_ * 16 + r0;                   \
        dst[fj_][0] = *(const bf16x8*)(ldsb + (CURB) + 32768 + col_ * 128 + ch0); \
        dst[fj_][1] = *(const bf16x8*)(ldsb + (CURB) + 32768 + col_ * 128 + ch1); \
    }                                                                           \
} while (0)

#define MFMA_Q(aq, bq, BF)                                                      \
    _Pragma("unroll")                                                           \
    for (int fl_ = 0; fl_ < 4; ++fl_) {                                         \
        _Pragma("unroll")                                                       \
        for (int fj_ = 0; fj_ < 2; ++fj_) {                                     \
            acc[(aq) * 4 + fl_][(bq) * 2 + fj_] =                               \
                __builtin_amdgcn_mfma_f32_16x16x32_bf16(af[fl_][0], BF[fj_][0], \
                    acc[(aq) * 4 + fl_][(bq) * 2 + fj_], 0, 0, 0);              \
            acc[(aq) * 4 + fl_][(bq) * 2 + fj_] =                               \
                __builtin_amdgcn_mfma_f32_16x16x32_bf16(af[fl_][1], BF[fj_][1], \
                    acc[(aq) * 4 + fl_][(bq) * 2 + fj_], 0, 0, 0);              \
        }                                                                       \
    }

#define BARRIER_MFMA(aq, bq, BF, WAITSTMT) do {                                 \
    __builtin_amdgcn_s_barrier();                                               \
    asm volatile("s_waitcnt lgkmcnt(0)" ::: "memory");                          \
    __builtin_amdgcn_sched_barrier(0);                                          \
    __builtin_amdgcn_s_setprio(1);                                              \
    MFMA_Q(aq, bq, BF);                                                         \
    __builtin_amdgcn_s_setprio(0);                                              \
    WAITSTMT;                                                                   \
    __builtin_amdgcn_s_barrier();                                               \
} while (0)

#define TILE(t, CURB, NXTB) do {                                                \
    const int kN1_ = ((t) + 1) * 64, kN2_ = ((t) + 2) * 64;                     \
    /* P1: Q(0,0); stage B1(t+1) */                                             \
    RD_A(CURB, 0); RD_B(CURB, 0, bf0);                                          \
    if ((t) + 1 < 16) STAGE_H((NXTB) + 49152, Bb + 128 * DDIM, kN1_);           \
    BARRIER_MFMA(0, 0, bf0, );                                                  \
    /* P2: Q(0,1); stage A1(t+1) */                                             \
    RD_B(CURB, 1, bf1);                                                         \
    if ((t) + 1 < 16) STAGE_H((NXTB) + 16384, Ab + 128 * DDIM, kN1_);           \
    BARRIER_MFMA(0, 1, bf1, );                                                  \
    /* P3: Q(1,1); stage B0(t+2) */                                             \
    RD_A(CURB, 1);                                                              \
    if ((t) + 2 < 16) STAGE_H((CURB) + 32768, Bb, kN2_);                        \
    BARRIER_MFMA(1, 1, bf1, );                                                  \
    /* P4: Q(1,0); stage A0(t+2); counted wait */                               \
    if ((t) + 2 < 16) STAGE_H((CURB) + 0, Ab, kN2_);                            \
    BARRIER_MFMA(1, 0, bf0,                                                     \
        if ((t) < 14) { asm volatile("s_waitcnt vmcnt(4)" ::: "memory"); }      \
        else if ((t) == 14) { asm volatile("s_waitcnt vmcnt(0)" ::: "memory"); });\
} while (0)

__global__ __launch_bounds__(512, 2) void cham_gemm_kernel(
    const unsigned short* __restrict__ A,   // set1 bf16 [4096][1024]
    const unsigned short* __restrict__ B,   // set2 bf16 [4096][1024]
    const float* __restrict__ x2, const float* __restrict__ y2,
    unsigned int* __restrict__ rowmin, unsigned int* __restrict__ colmin) {
    __shared__ __align__(16) char lds[131072];
    char* ldsb = lds;

    const int bi = blockIdx.x & 15;
    const int bj = blockIdx.x >> 4;
    const int tid = threadIdx.x;
    const int wave = tid >> 6;
    const int lane = tid & 63;
    const int wr = wave >> 2;          // 0..1 (128 rows)
    const int wc = wave & 3;           // 0..3 (64 cols)
    const int r0 = lane & 15;
    const int q = lane >> 4;           // 0..3

    // lane-constant swizzled chunk byte offsets for k-half 0 / 1
    const int ch0 = ((q ^ (r0 & 7)) << 4);
    const int ch1 = (((4 + q) ^ (r0 & 7)) << 4);

    // staging lane constants
    const int srow = lane >> 3;                    // 0..7
    const int schoff = (((lane & 7) ^ srow) * 8);  // element offset (x8 bf16)

    const unsigned short* Ab = A + (size_t)(bi * 256) * DDIM;
    const unsigned short* Bb = B + (size_t)(bj * 256) * DDIM;

    f32x4 acc[8][4];
    #pragma unroll
    for (int i = 0; i < 8; ++i)
        #pragma unroll
        for (int j = 0; j < 4; ++j)
            acc[i][j] = (f32x4){0.f, 0.f, 0.f, 0.f};

    bf16x8 af[4][2], bf0[2][2], bf1[2][2];

    // prologue: B0(0),A0(0),B1(0),A1(0),B0(1),A0(1); allow last 2 halves out.
    STAGE_H(0 + 32768, Bb, 0);
    STAGE_H(0 + 0, Ab, 0);
    STAGE_H(0 + 49152, Bb + 128 * DDIM, 0);
    STAGE_H(0 + 16384, Ab + 128 * DDIM, 0);
    STAGE_H(65536 + 32768, Bb, 64);
    STAGE_H(65536 + 0, Ab, 64);
    asm volatile("s_waitcnt vmcnt(4)" ::: "memory");
    __builtin_amdgcn_s_barrier();

    for (int tt = 0; tt < 8; ++tt) {
        const int te = 2 * tt, to = 2 * tt + 1;
        TILE(te, 0, 65536);
        TILE(to, 65536, 0);
    }

    // ---- epilogue: dist = (x2[n] + y2[m] - 2*xy)/D, fused row/col mins
    const float invD = 1.0f / (float)DDIM;
    const int nb = bi * 256 + wr * 128;
    const int mb = bj * 256 + wc * 64;

    float y2v[4];
    #pragma unroll
    for (int fj = 0; fj < 4; ++fj)
        y2v[fj] = y2[mb + (fj >> 1) * 32 + (fj & 1) * 16 + r0];

    float cv[4];
    #pragma unroll
    for (int fj = 0; fj < 4; ++fj) cv[fj] = 3.0e38f;

    #pragma unroll
    for (int fi = 0; fi < 8; ++fi) {
        #pragma unroll
        for (int rg = 0; rg < 4; ++rg) {
            const int n = nb + fi * 16 + q * 4 + rg;
            const float x2v = x2[n];
            float rv = 3.0e38f;
            #pragma unroll
            for (int fj = 0; fj < 4; ++fj) {
                float d = (x2v + y2v[fj] - 2.0f * acc[fi][fj][rg]) * invD;
                rv = fminf(rv, d);
                cv[fj] = fminf(cv[fj], d);
            }
            rv = fminf(rv, __shfl_xor(rv, 1, 64));
            rv = fminf(rv, __shfl_xor(rv, 2, 64));
            rv = fminf(rv, __shfl_xor(rv, 4, 64));
            rv = fminf(rv, __shfl_xor(rv, 8, 64));
            if (r0 == 0) atomicMin(&rowmin[n], __float_as_uint(rv));
        }
    }

    #pragma unroll
    for (int fj = 0; fj < 4; ++fj) {
        float v = cv[fj];
        v = fminf(v, __shfl_xor(v, 16, 64));
        v = fminf(v, __shfl_xor(v, 32, 64));
        if (lane < 16)
            atomicMin(&colmin[mb + (fj >> 1) * 32 + (fj & 1) * 16 + lane],
                      __float_as_uint(v));
    }
}

// ---------------- final reduction ------------------------------------------
__global__ __launch_bounds__(1024) void finredux_kernel(
    const unsigned int* __restrict__ mins /* 8192 */, float* __restrict__ out) {
    int t = threadIdx.x;
    float s = 0.f;
    #pragma unroll
    for (int i = 0; i < 8; ++i) s += __uint_as_float(mins[t + i * 1024]);
    #pragma unroll
    for (int off = 32; off; off >>= 1) s += __shfl_down(s, off, 64);
    __shared__ float ws_[16];
    if ((t & 63) == 0) ws_[t >> 6] = s;
    __syncthreads();
    if (t == 0) {
        float tot = 0.f;
        #pragma unroll
        for (int i = 0; i < 16; ++i) tot += ws_[i];
        out[0] = tot * (1.0f / 8192.0f);
    }
}

extern "C" void kernel_launch(void* const* d_in, const int* in_sizes, int n_in,
                              void* d_out, int out_size, void* d_ws, size_t ws_size,
                              hipStream_t stream) {
    const float* s1 = (const float*)d_in[0];
    const float* s2 = (const float*)d_in[1];
    char* ws = (char*)d_ws;

    unsigned short* b1 = (unsigned short*)ws;                         //  8 MB
    unsigned short* b2 = (unsigned short*)(ws + 8388608);             //  8 MB
    float* norms       = (float*)(ws + 16777216);                     // 32 KB
    unsigned int* mins = (unsigned int*)(ws + 16777216 + 32768);      // 32 KB
    float* out = (float*)d_out;

    prepass_kernel<<<2048, 256, 0, stream>>>(s1, s2, b1, b2, norms, mins);
    cham_gemm_kernel<<<256, 512, 0, stream>>>(b1, b2, norms, norms + NPTS,
                                              mins, mins + NPTS);
    finredux_kernel<<<1, 1024, 0, stream>>>(mins, out);
}